// Round 17
// baseline (316.526 us; speedup 1.0000x reference)
//
#include <hip/hip_runtime.h>
#include <math.h>

// GAT 2-layer: N=10000, E=160000 (+N self loops), IN=128, H1=8, C1=128, OUT=64.
// R17: l1_gather fused into l12_gemm as phase 0 (A-fragments gathered straight
//      into registers; y_b buffer deleted, 40 MB round-trip gone). 6 dispatches.
// GEMMs bf16 MFMA (fp32 accumulate); softmax path fp32.

#define NEG_SLOPE 0.2f

typedef short bf16x8 __attribute__((ext_vector_type(8)));
typedef float f32x4 __attribute__((ext_vector_type(4)));

__device__ __forceinline__ float leaky(float v) { return v >= 0.0f ? v : NEG_SLOPE * v; }

__device__ __forceinline__ unsigned short f2bf(float f) {
    unsigned u = __float_as_uint(f);
    u += 0x7FFFu + ((u >> 16) & 1u);   // round-to-nearest-even
    return (unsigned short)(u >> 16);
}

// ---------------- kernel 1: prep (As_t/Ad_t, W1bT, W2bT) + edge count ----------------

__global__ __launch_bounds__(256) void prep_count(
    const float* __restrict__ W1, const float* __restrict__ a_src1,
    const float* __restrict__ a_dst1, const float* __restrict__ W2,
    const int* __restrict__ ei,
    float* __restrict__ As_t, float* __restrict__ Ad_t,
    unsigned short* __restrict__ W1bT, unsigned short* __restrict__ W2bT,
    int* __restrict__ counts, int E, int N) {
    int b = blockIdx.x;
    __shared__ unsigned short tile[32][33];
    if (b < 4) {
        int i = b * 256 + threadIdx.x;   // 0..1023
        int k = i >> 3, h = i & 7;
        float ss = 0.f, sd = 0.f;
        for (int c = 0; c < 128; c += 4) {
            float4 w = *(const float4*)(W1 + (size_t)k * 1024 + h * 128 + c);
            float4 a = *(const float4*)(a_src1 + h * 128 + c);
            float4 d = *(const float4*)(a_dst1 + h * 128 + c);
            ss += w.x * a.x + w.y * a.y + w.z * a.z + w.w * a.w;
            sd += w.x * d.x + w.y * d.y + w.z * d.z + w.w * d.w;
        }
        As_t[h * 132 + k] = ss;   // transposed, stride 132 (bank stagger)
        Ad_t[h * 132 + k] = sd;
    } else if (b < 132) {
        int bb = b - 4;
        int kt = bb & 3, hct = bb >> 2;
        int j = threadIdx.x & 31;
        int i0 = threadIdx.x >> 5;
        for (int i = i0; i < 32; i += 8)
            tile[i][j] = f2bf(W1[(size_t)(kt * 32 + i) * 1024 + hct * 32 + j]);
        __syncthreads();
        for (int i = i0; i < 32; i += 8) {
            int hc = hct * 32 + i, k = kt * 32 + j;
            int h = hc >> 7, c = hc & 127;
            W1bT[h * 16384 + c * 128 + k] = tile[j][i];
        }
    } else if (b < 196) {
        int bb = b - 132;
        int kt = bb & 31, ctile = bb >> 5;
        int j = threadIdx.x & 31;
        int i0 = threadIdx.x >> 5;
        for (int i = i0; i < 32; i += 8)
            tile[i][j] = f2bf(W2[(size_t)(kt * 32 + i) * 64 + ctile * 32 + j]);
        __syncthreads();
        for (int i = i0; i < 32; i += 8)
            W2bT[(size_t)(ctile * 32 + i) * 1024 + kt * 32 + j] = tile[j][i];
    } else {
        int i = (b - 196) * 256 + threadIdx.x;
        int M = E + N;
        if (i >= M) return;
        int dst = (i < E) ? ei[E + i] : (i - E);   // self-loop tail
        atomicAdd(&counts[dst], 1);
    }
}

// ---------------- kernel 2: alpha1 + scan (last block) ----------------

__global__ __launch_bounds__(1024) void alpha_scan(
    const float* __restrict__ x, const float* __restrict__ As_t, const float* __restrict__ Ad_t,
    float* __restrict__ as1, float* __restrict__ ad1,
    const int* __restrict__ counts, int* __restrict__ offsets,
    int* __restrict__ cursor, int N, int nb_alpha) {
    int t = threadIdx.x;
    if ((int)blockIdx.x < nb_alpha) {
        __shared__ float sAs[1056], sAd[1056];
        for (int i = t; i < 1056; i += 1024) {
            sAs[i] = As_t[i];
            sAd[i] = Ad_t[i];
        }
        __syncthreads();
        int node = blockIdx.x * 128 + (t >> 3);
        int h = t & 7;
        if (node >= N) return;
        const float* sa = sAs + h * 132;
        const float* sd = sAd + h * 132;
        float accs = 0.f, accd = 0.f;
        for (int k = 0; k < 128; k += 4) {
            float4 xv = *(const float4*)(x + (size_t)node * 128 + k);
            float4 av = *(const float4*)(sa + k);
            float4 dv = *(const float4*)(sd + k);
            accs += xv.x * av.x + xv.y * av.y + xv.z * av.z + xv.w * av.w;
            accd += xv.x * dv.x + xv.y * dv.y + xv.z * dv.z + xv.w * dv.w;
        }
        as1[node * 8 + h] = accs;
        ad1[node * 8 + h] = accd;
    } else {
        __shared__ int wsum[16];
        int per = (N + 1023) / 1024;
        int base = t * per;
        int s = 0;
        for (int j = 0; j < per; j++) {
            int idx = base + j;
            if (idx < N) s += counts[idx];
        }
        int lane = t & 63, wid = t >> 6;
        int inc = s;
#pragma unroll
        for (int off = 1; off <= 32; off <<= 1) {
            int v = __shfl_up(inc, off);
            if (lane >= off) inc += v;
        }
        if (lane == 63) wsum[wid] = inc;
        __syncthreads();
        if (t < 16) {
            int v = wsum[t];
            int iv = v;
#pragma unroll
            for (int off = 1; off <= 8; off <<= 1) {
                int u = __shfl_up(iv, off);
                if (t >= off) iv += u;
            }
            wsum[t] = iv - v;   // exclusive
        }
        __syncthreads();
        int run = wsum[wid] + inc - s;
        for (int j = 0; j < per; j++) {
            int idx = base + j;
            if (idx < N) {
                offsets[idx] = run;
                cursor[idx] = run;
                run += counts[idx];
            }
        }
        if (t == 1023) offsets[N] = run;
    }
}

// ---------------- kernel 3: fill CSR + inline layer-1 softmax numerators ---------

__global__ __launch_bounds__(256) void fill_w1(
    const int* __restrict__ ei, int* __restrict__ cursor,
    const float* __restrict__ as1, const float* __restrict__ ad1,
    int* __restrict__ srcs, float* __restrict__ wbuf, int E, int N) {
    int i = blockIdx.x * blockDim.x + threadIdx.x;
    int M = E + N;
    if (i >= M) return;
    int src, dst;
    if (i < E) { src = ei[i]; dst = ei[E + i]; }
    else       { src = dst = i - E; }
    int pos = atomicAdd(&cursor[dst], 1);
    srcs[pos] = src;
    float4 a0 = *(const float4*)(as1 + (size_t)src * 8);
    float4 a1 = *(const float4*)(as1 + (size_t)src * 8 + 4);
    float4 b0 = *(const float4*)(ad1 + (size_t)dst * 8);
    float4 b1 = *(const float4*)(ad1 + (size_t)dst * 8 + 4);
    float4 w0, w1;
    w0.x = __expf(leaky(a0.x + b0.x));
    w0.y = __expf(leaky(a0.y + b0.y));
    w0.z = __expf(leaky(a0.z + b0.z));
    w0.w = __expf(leaky(a0.w + b0.w));
    w1.x = __expf(leaky(a1.x + b1.x));
    w1.y = __expf(leaky(a1.y + b1.y));
    w1.z = __expf(leaky(a1.z + b1.z));
    w1.w = __expf(leaky(a1.w + b1.w));
    *(float4*)(wbuf + (size_t)pos * 8)     = w0;
    *(float4*)(wbuf + (size_t)pos * 8 + 4) = w1;
}

// ---------------- l12_gemm (fused gather + 2 GEMMs, 512 threads) -----------------
// Block = 16 nodes. Wave w = head w.
// Phase 0: lane (n16, quad) gathers its node's A-fragment channels
//          {quad*8 + ks*32 + j} of head w directly into registers (edge loop over
//          srcs/wbuf; in-register wsum; bf16 pack). No y buffer.
// Phase A: 8 col-tiles of ELU(y@W1+b1) per wave -> LDS hb (stride 1032: <=2-way).
// Phase B: ct2 = w&3 (16 cols), K-half kh = w>>2, LDS reduce; alpha2 epilogue.

__global__ __launch_bounds__(512) void l12_gemm(
    const float* __restrict__ x, const float* __restrict__ wbuf,
    const int* __restrict__ offsets, const int* __restrict__ srcs,
    const unsigned short* __restrict__ W1bT, const float* __restrict__ b1,
    const unsigned short* __restrict__ W2bT,
    const float* __restrict__ a_src2, const float* __restrict__ a_dst2,
    float* __restrict__ h2, float* __restrict__ as2, float* __restrict__ ad2, int N) {
    int nb = blockIdx.x * 16;
    int w = threadIdx.x >> 6;        // 0..7 = head
    int lane = threadIdx.x & 63;
    int n16 = lane & 15, quad = lane >> 4;
    __shared__ unsigned short hb[16 * 1032];   // 33 KB
    __shared__ float red[4][64][4];            // 4 KB
    __shared__ float sA[4][16], sD[4][16];
    // ---- phase 0: gather A-fragments ----
    int node = nb + n16;
    bool vn = node < N;
    int beg = vn ? offsets[node] : 0;
    int deg = vn ? (offsets[node + 1] - beg) : 0;
    float a0[32];
#pragma unroll
    for (int q = 0; q < 32; q++) a0[q] = 0.f;
    float wsum = 0.f;
    const float* xq = x + quad * 8;
#define P0_BODY(I)                                                           \
    {                                                                        \
        int s_ = srcs[beg + (I)];                                            \
        float we_ = wbuf[(size_t)(beg + (I)) * 8 + w];                       \
        wsum += we_;                                                         \
        const float* xr_ = xq + (size_t)s_ * 128;                            \
        _Pragma("unroll")                                                    \
        for (int ks = 0; ks < 4; ks++) {                                     \
            float4 v0_ = *(const float4*)(xr_ + ks * 32);                    \
            float4 v1_ = *(const float4*)(xr_ + ks * 32 + 4);                \
            a0[ks * 8 + 0] = fmaf(we_, v0_.x, a0[ks * 8 + 0]);               \
            a0[ks * 8 + 1] = fmaf(we_, v0_.y, a0[ks * 8 + 1]);               \
            a0[ks * 8 + 2] = fmaf(we_, v0_.z, a0[ks * 8 + 2]);               \
            a0[ks * 8 + 3] = fmaf(we_, v0_.w, a0[ks * 8 + 3]);               \
            a0[ks * 8 + 4] = fmaf(we_, v1_.x, a0[ks * 8 + 4]);               \
            a0[ks * 8 + 5] = fmaf(we_, v1_.y, a0[ks * 8 + 5]);               \
            a0[ks * 8 + 6] = fmaf(we_, v1_.z, a0[ks * 8 + 6]);               \
            a0[ks * 8 + 7] = fmaf(we_, v1_.w, a0[ks * 8 + 7]);               \
        }                                                                    \
    }
    int i = 0;
    for (; i + 2 <= deg; i += 2) { P0_BODY(i) P0_BODY(i + 1) }
    for (; i < deg; i++) { P0_BODY(i) }
#undef P0_BODY
    float inv = 1.0f / (wsum + 1e-16f);
    bf16x8 af[4];
#pragma unroll
    for (int ks = 0; ks < 4; ks++) {
        union { bf16x8 v; unsigned short u[8]; } tmp;
#pragma unroll
        for (int j = 0; j < 8; j++) tmp.u[j] = f2bf(a0[ks * 8 + j] * inv);
        af[ks] = tmp.v;
    }
    // ---- phase A: head w, columns w*128 .. w*128+127 ----
#pragma unroll
    for (int cti = 0; cti < 8; cti++) {
        int cc = cti * 16;
        const unsigned short* Wh = W1bT + w * 16384 + (size_t)(cc + n16) * 128 + quad * 8;
        f32x4 acc = (f32x4){0.f, 0.f, 0.f, 0.f};
#pragma unroll
        for (int ks = 0; ks < 4; ks++) {
            bf16x8 b = *(const bf16x8*)(Wh + ks * 32);
            acc = __builtin_amdgcn_mfma_f32_16x16x32_bf16(af[ks], b, acc, 0, 0, 0);
        }
        int c = w * 128 + cc + n16;     // global channel 0..1023
        float bias = b1[c];
#pragma unroll
        for (int r = 0; r < 4; r++) {
            float v = acc[r] + bias;
            v = v > 0.f ? v : expm1f(v);
            hb[(quad * 4 + r) * 1032 + c] = f2bf(v);
        }
    }
    __syncthreads();
    // ---- phase B: ct2 = w&3 (16 cols), kh = w>>2 (K-half of 512) ----
    int ct2 = w & 3, kh = w >> 2;
    const unsigned short* arow = hb + n16 * 1032 + kh * 512 + quad * 8;
    const unsigned short* brow = W2bT + (size_t)(ct2 * 16 + n16) * 1024 + kh * 512 + quad * 8;
    f32x4 acc = (f32x4){0.f, 0.f, 0.f, 0.f};
#pragma unroll
    for (int ks = 0; ks < 16; ks++) {
        bf16x8 a = *(const bf16x8*)(arow + ks * 32);
        bf16x8 b = *(const bf16x8*)(brow + ks * 32);
        acc = __builtin_amdgcn_mfma_f32_16x16x32_bf16(a, b, acc, 0, 0, 0);
    }
    if (kh == 1) {
#pragma unroll
        for (int r = 0; r < 4; r++) red[ct2][lane][r] = acc[r];
    }
    __syncthreads();
    if (kh == 0) {
#pragma unroll
        for (int r = 0; r < 4; r++) acc[r] += red[ct2][lane][r];
        int c2 = ct2 * 16 + n16;
        float asc = a_src2[c2], adc = a_dst2[c2];
        float pav[4], pdv[4];
#pragma unroll
        for (int r = 0; r < 4; r++) {
            int nd = nb + quad * 4 + r;
            if (nd < N) h2[(size_t)nd * 64 + c2] = acc[r];
            pav[r] = acc[r] * asc;
            pdv[r] = acc[r] * adc;
#pragma unroll
            for (int mm = 1; mm <= 8; mm <<= 1) {   // reduce over the 16 n16 lanes
                pav[r] += __shfl_xor(pav[r], mm);
                pdv[r] += __shfl_xor(pdv[r], mm);
            }
        }
        if (n16 == 0) {
#pragma unroll
            for (int r = 0; r < 4; r++) {
                sA[ct2][quad * 4 + r] = pav[r];
                sD[ct2][quad * 4 + r] = pdv[r];
            }
        }
    }
    __syncthreads();
    if (threadIdx.x < 16) {
        int nd = nb + threadIdx.x;
        if (nd < N) {
            as2[nd] = sA[0][threadIdx.x] + sA[1][threadIdx.x] + sA[2][threadIdx.x] + sA[3][threadIdx.x];
            ad2[nd] = sD[0][threadIdx.x] + sD[1][threadIdx.x] + sD[2][threadIdx.x] + sD[3][threadIdx.x];
        }
    }
}

// ---------------- l2_gather: wave per node, inline weights, in-register wsum -----

__global__ __launch_bounds__(256) void l2_gather(
    const float* __restrict__ h2, const float* __restrict__ as2,
    const float* __restrict__ ad2, const float* __restrict__ b2,
    const int* __restrict__ offsets, const int* __restrict__ srcs,
    float* __restrict__ out, int N) {
    int n = blockIdx.x * 4 + (threadIdx.x >> 6);
    if (n >= N) return;
    int lane = threadIdx.x & 63;
    int beg = offsets[n];
    int deg = offsets[n + 1] - beg;
    float adn = ad2[n];
    float acc = 0.f, wsum = 0.f;
    int i = 0;
    for (; i + 4 <= deg; i += 4) {
        int s0 = srcs[beg + i],     s1 = srcs[beg + i + 1];
        int s2 = srcs[beg + i + 2], s3 = srcs[beg + i + 3];
        float w0 = __expf(leaky(as2[s0] + adn));   // same addr all lanes -> broadcast
        float w1 = __expf(leaky(as2[s1] + adn));
        float w2 = __expf(leaky(as2[s2] + adn));
        float w3 = __expf(leaky(as2[s3] + adn));
        float v0 = h2[(size_t)s0 * 64 + lane];
        float v1 = h2[(size_t)s1 * 64 + lane];
        float v2 = h2[(size_t)s2 * 64 + lane];
        float v3 = h2[(size_t)s3 * 64 + lane];
        wsum += w0 + w1 + w2 + w3;
        acc = fmaf(w0, v0, acc);
        acc = fmaf(w1, v1, acc);
        acc = fmaf(w2, v2, acc);
        acc = fmaf(w3, v3, acc);
    }
    for (; i < deg; i++) {
        int s = srcs[beg + i];
        float w = __expf(leaky(as2[s] + adn));
        wsum += w;
        acc = fmaf(w, h2[(size_t)s * 64 + lane], acc);
    }
    out[(size_t)n * 64 + lane] = acc / (wsum + 1e-16f) + b2[lane];
}

// ---------------- launch ----------------

static inline size_t align_up(size_t v, size_t a) { return (v + a - 1) / a * a; }

extern "C" void kernel_launch(void* const* d_in, const int* in_sizes, int n_in,
                              void* d_out, int out_size, void* d_ws, size_t ws_size,
                              hipStream_t stream) {
    const float* x      = (const float*)d_in[0];
    const int*   ei     = (const int*)d_in[1];
    const float* W1     = (const float*)d_in[2];
    const float* a_src1 = (const float*)d_in[3];
    const float* a_dst1 = (const float*)d_in[4];
    const float* b1     = (const float*)d_in[5];
    const float* W2     = (const float*)d_in[6];
    const float* a_src2 = (const float*)d_in[7];
    const float* a_dst2 = (const float*)d_in[8];
    const float* b2     = (const float*)d_in[9];
    float* out = (float*)d_out;

    int N = in_sizes[0] / 128;
    int E = in_sizes[1] / 2;
    int M = E + N;

    char* p = (char*)d_ws;
    size_t off = 0;
    auto carve = [&](size_t bytes) {
        void* r = p + off;
        off = align_up(off + bytes, 256);
        return r;
    };
    int*            counts  = (int*)carve((size_t)N * 4);
    int*            offsets = (int*)carve((size_t)(N + 1) * 4);
    int*            cursor  = (int*)carve((size_t)N * 4);
    int*            srcs    = (int*)carve((size_t)M * 4);
    float*          As_t    = (float*)carve(1056 * 4);
    float*          Ad_t    = (float*)carve(1056 * 4);
    float*          as1     = (float*)carve((size_t)N * 8 * 4);
    float*          ad1     = (float*)carve((size_t)N * 8 * 4);
    float*          as2     = (float*)carve((size_t)N * 4);
    float*          ad2     = (float*)carve((size_t)N * 4);
    float*          h2      = (float*)carve((size_t)N * 64 * 4);
    float*          wbuf    = (float*)carve((size_t)M * 8 * 4);
    unsigned short* W1bT    = (unsigned short*)carve((size_t)8 * 128 * 128 * 2);
    unsigned short* W2bT    = (unsigned short*)carve((size_t)64 * 1024 * 2);
    (void)ws_size; // ~20 MB

    int nb_count = (M + 255) / 256;
    int nb_alpha = (N + 127) / 128;

    hipMemsetAsync(counts, 0, (size_t)N * 4, stream);
    prep_count<<<196 + nb_count, 256, 0, stream>>>(W1, a_src1, a_dst1, W2, ei,
                                                   As_t, Ad_t, W1bT, W2bT, counts, E, N);
    alpha_scan<<<nb_alpha + 1, 1024, 0, stream>>>(x, As_t, Ad_t, as1, ad1,
                                                  counts, offsets, cursor, N, nb_alpha);
    fill_w1<<<nb_count, 256, 0, stream>>>(ei, cursor, as1, ad1, srcs, wbuf, E, N);
    l12_gemm<<<(N + 15) / 16, 512, 0, stream>>>(x, wbuf, offsets, srcs,
                                                W1bT, b1, W2bT, a_src2, a_dst2,
                                                h2, as2, ad2, N);
    l2_gather<<<(N + 3) / 4, 256, 0, stream>>>(h2, as2, ad2, b2, offsets, srcs, out, N);
}

// Round 18
// 192.842 us; speedup vs baseline: 1.6414x; 1.6414x over previous
//
#include <hip/hip_runtime.h>
#include <math.h>

// GAT 2-layer: N=10000, E=160000 (+N self loops), IN=128, H1=8, C1=128, OUT=64.
// R18 = R15 revert (best measured: 192.8 us). 7 dispatches:
//   [memset] [prep+count] [alpha1+scan] [fill+w1] [l1_gather] [l12_gemm] [l2_gather]
// GEMMs bf16 MFMA (fp32 accumulate); softmax path fp32.
// R16 (8-wave l12) and R17 (gather fused into l12) both regressed -- the
// cooperative per-node gather wave (l1_gather) is load-bearing.

#define NEG_SLOPE 0.2f

typedef short bf16x8 __attribute__((ext_vector_type(8)));
typedef float f32x4 __attribute__((ext_vector_type(4)));

__device__ __forceinline__ float leaky(float v) { return v >= 0.0f ? v : NEG_SLOPE * v; }

__device__ __forceinline__ unsigned short f2bf(float f) {
    unsigned u = __float_as_uint(f);
    u += 0x7FFFu + ((u >> 16) & 1u);   // round-to-nearest-even
    return (unsigned short)(u >> 16);
}

// ---------------- kernel 1: prep (As_t/Ad_t, W1bT, W2bT) + edge count ----------------

__global__ __launch_bounds__(256) void prep_count(
    const float* __restrict__ W1, const float* __restrict__ a_src1,
    const float* __restrict__ a_dst1, const float* __restrict__ W2,
    const int* __restrict__ ei,
    float* __restrict__ As_t, float* __restrict__ Ad_t,
    unsigned short* __restrict__ W1bT, unsigned short* __restrict__ W2bT,
    int* __restrict__ counts, int E, int N) {
    int b = blockIdx.x;
    __shared__ unsigned short tile[32][33];
    if (b < 4) {
        int i = b * 256 + threadIdx.x;   // 0..1023
        int k = i >> 3, h = i & 7;
        float ss = 0.f, sd = 0.f;
        for (int c = 0; c < 128; c += 4) {
            float4 w = *(const float4*)(W1 + (size_t)k * 1024 + h * 128 + c);
            float4 a = *(const float4*)(a_src1 + h * 128 + c);
            float4 d = *(const float4*)(a_dst1 + h * 128 + c);
            ss += w.x * a.x + w.y * a.y + w.z * a.z + w.w * a.w;
            sd += w.x * d.x + w.y * d.y + w.z * d.z + w.w * d.w;
        }
        As_t[h * 132 + k] = ss;   // transposed, stride 132 (bank stagger)
        Ad_t[h * 132 + k] = sd;
    } else if (b < 132) {
        int bb = b - 4;
        int kt = bb & 3, hct = bb >> 2;
        int j = threadIdx.x & 31;
        int i0 = threadIdx.x >> 5;
        for (int i = i0; i < 32; i += 8)
            tile[i][j] = f2bf(W1[(size_t)(kt * 32 + i) * 1024 + hct * 32 + j]);
        __syncthreads();
        for (int i = i0; i < 32; i += 8) {
            int hc = hct * 32 + i, k = kt * 32 + j;
            int h = hc >> 7, c = hc & 127;
            W1bT[h * 16384 + c * 128 + k] = tile[j][i];
        }
    } else if (b < 196) {
        int bb = b - 132;
        int kt = bb & 31, ctile = bb >> 5;
        int j = threadIdx.x & 31;
        int i0 = threadIdx.x >> 5;
        for (int i = i0; i < 32; i += 8)
            tile[i][j] = f2bf(W2[(size_t)(kt * 32 + i) * 64 + ctile * 32 + j]);
        __syncthreads();
        for (int i = i0; i < 32; i += 8)
            W2bT[(size_t)(ctile * 32 + i) * 1024 + kt * 32 + j] = tile[j][i];
    } else {
        int i = (b - 196) * 256 + threadIdx.x;
        int M = E + N;
        if (i >= M) return;
        int dst = (i < E) ? ei[E + i] : (i - E);   // self-loop tail
        atomicAdd(&counts[dst], 1);
    }
}

// ---------------- kernel 2: alpha1 + scan (last block) ----------------

__global__ __launch_bounds__(1024) void alpha_scan(
    const float* __restrict__ x, const float* __restrict__ As_t, const float* __restrict__ Ad_t,
    float* __restrict__ as1, float* __restrict__ ad1,
    const int* __restrict__ counts, int* __restrict__ offsets,
    int* __restrict__ cursor, int N, int nb_alpha) {
    int t = threadIdx.x;
    if ((int)blockIdx.x < nb_alpha) {
        __shared__ float sAs[1056], sAd[1056];
        for (int i = t; i < 1056; i += 1024) {
            sAs[i] = As_t[i];
            sAd[i] = Ad_t[i];
        }
        __syncthreads();
        int node = blockIdx.x * 128 + (t >> 3);
        int h = t & 7;
        if (node >= N) return;
        const float* sa = sAs + h * 132;
        const float* sd = sAd + h * 132;
        float accs = 0.f, accd = 0.f;
        for (int k = 0; k < 128; k += 4) {
            float4 xv = *(const float4*)(x + (size_t)node * 128 + k);
            float4 av = *(const float4*)(sa + k);
            float4 dv = *(const float4*)(sd + k);
            accs += xv.x * av.x + xv.y * av.y + xv.z * av.z + xv.w * av.w;
            accd += xv.x * dv.x + xv.y * dv.y + xv.z * dv.z + xv.w * dv.w;
        }
        as1[node * 8 + h] = accs;
        ad1[node * 8 + h] = accd;
    } else {
        __shared__ int wsum[16];
        int per = (N + 1023) / 1024;
        int base = t * per;
        int s = 0;
        for (int j = 0; j < per; j++) {
            int idx = base + j;
            if (idx < N) s += counts[idx];
        }
        int lane = t & 63, wid = t >> 6;
        int inc = s;
#pragma unroll
        for (int off = 1; off <= 32; off <<= 1) {
            int v = __shfl_up(inc, off);
            if (lane >= off) inc += v;
        }
        if (lane == 63) wsum[wid] = inc;
        __syncthreads();
        if (t < 16) {
            int v = wsum[t];
            int iv = v;
#pragma unroll
            for (int off = 1; off <= 8; off <<= 1) {
                int u = __shfl_up(iv, off);
                if (t >= off) iv += u;
            }
            wsum[t] = iv - v;   // exclusive
        }
        __syncthreads();
        int run = wsum[wid] + inc - s;
        for (int j = 0; j < per; j++) {
            int idx = base + j;
            if (idx < N) {
                offsets[idx] = run;
                cursor[idx] = run;
                run += counts[idx];
            }
        }
        if (t == 1023) offsets[N] = run;
    }
}

// ---------------- kernel 3: fill CSR + inline layer-1 softmax numerators ---------

__global__ __launch_bounds__(256) void fill_w1(
    const int* __restrict__ ei, int* __restrict__ cursor,
    const float* __restrict__ as1, const float* __restrict__ ad1,
    int* __restrict__ srcs, float* __restrict__ wbuf, int E, int N) {
    int i = blockIdx.x * blockDim.x + threadIdx.x;
    int M = E + N;
    if (i >= M) return;
    int src, dst;
    if (i < E) { src = ei[i]; dst = ei[E + i]; }
    else       { src = dst = i - E; }
    int pos = atomicAdd(&cursor[dst], 1);
    srcs[pos] = src;
    float4 a0 = *(const float4*)(as1 + (size_t)src * 8);
    float4 a1 = *(const float4*)(as1 + (size_t)src * 8 + 4);
    float4 b0 = *(const float4*)(ad1 + (size_t)dst * 8);
    float4 b1 = *(const float4*)(ad1 + (size_t)dst * 8 + 4);
    float4 w0, w1;
    w0.x = __expf(leaky(a0.x + b0.x));
    w0.y = __expf(leaky(a0.y + b0.y));
    w0.z = __expf(leaky(a0.z + b0.z));
    w0.w = __expf(leaky(a0.w + b0.w));
    w1.x = __expf(leaky(a1.x + b1.x));
    w1.y = __expf(leaky(a1.y + b1.y));
    w1.z = __expf(leaky(a1.z + b1.z));
    w1.w = __expf(leaky(a1.w + b1.w));
    *(float4*)(wbuf + (size_t)pos * 8)     = w0;
    *(float4*)(wbuf + (size_t)pos * 8 + 4) = w1;
}

// ---------------- l1_gather: wave per node, pure gather, in-register wsum --------

__global__ __launch_bounds__(256) void l1_gather(
    const float* __restrict__ x, const float* __restrict__ wbuf,
    const int* __restrict__ offsets, const int* __restrict__ srcs,
    unsigned short* __restrict__ y_b, int N) {
    int n = blockIdx.x * 4 + (threadIdx.x >> 6);
    if (n >= N) return;
    int lane = threadIdx.x & 63;
    int beg = offsets[n];
    int deg = offsets[n + 1] - beg;
    float2 acc[8];
#pragma unroll
    for (int h = 0; h < 8; h++) acc[h] = make_float2(0.f, 0.f);
    float4 ws0 = make_float4(0.f, 0.f, 0.f, 0.f);
    float4 ws1 = make_float4(0.f, 0.f, 0.f, 0.f);
    const float* xb = x + lane * 2;
#define L1G_BODY(I)                                                              \
    {                                                                            \
        int s_ = srcs[beg + (I)];                                                \
        float4 w0_ = *(const float4*)(wbuf + (size_t)(beg + (I)) * 8);           \
        float4 w1_ = *(const float4*)(wbuf + (size_t)(beg + (I)) * 8 + 4);       \
        float2 xv_ = *(const float2*)(xb + (size_t)s_ * 128);                    \
        ws0.x += w0_.x; ws0.y += w0_.y; ws0.z += w0_.z; ws0.w += w0_.w;          \
        ws1.x += w1_.x; ws1.y += w1_.y; ws1.z += w1_.z; ws1.w += w1_.w;          \
        acc[0].x = fmaf(w0_.x, xv_.x, acc[0].x); acc[0].y = fmaf(w0_.x, xv_.y, acc[0].y); \
        acc[1].x = fmaf(w0_.y, xv_.x, acc[1].x); acc[1].y = fmaf(w0_.y, xv_.y, acc[1].y); \
        acc[2].x = fmaf(w0_.z, xv_.x, acc[2].x); acc[2].y = fmaf(w0_.z, xv_.y, acc[2].y); \
        acc[3].x = fmaf(w0_.w, xv_.x, acc[3].x); acc[3].y = fmaf(w0_.w, xv_.y, acc[3].y); \
        acc[4].x = fmaf(w1_.x, xv_.x, acc[4].x); acc[4].y = fmaf(w1_.x, xv_.y, acc[4].y); \
        acc[5].x = fmaf(w1_.y, xv_.x, acc[5].x); acc[5].y = fmaf(w1_.y, xv_.y, acc[5].y); \
        acc[6].x = fmaf(w1_.z, xv_.x, acc[6].x); acc[6].y = fmaf(w1_.z, xv_.y, acc[6].y); \
        acc[7].x = fmaf(w1_.w, xv_.x, acc[7].x); acc[7].y = fmaf(w1_.w, xv_.y, acc[7].y); \
    }
    int i = 0;
    for (; i + 4 <= deg; i += 4) {       // 4 edges in flight
        L1G_BODY(i) L1G_BODY(i + 1) L1G_BODY(i + 2) L1G_BODY(i + 3)
    }
    for (; i < deg; i++) { L1G_BODY(i) }
#undef L1G_BODY
    float inv[8] = {1.f / (ws0.x + 1e-16f), 1.f / (ws0.y + 1e-16f),
                    1.f / (ws0.z + 1e-16f), 1.f / (ws0.w + 1e-16f),
                    1.f / (ws1.x + 1e-16f), 1.f / (ws1.y + 1e-16f),
                    1.f / (ws1.z + 1e-16f), 1.f / (ws1.w + 1e-16f)};
    unsigned short* dst = y_b + (size_t)n * 1024 + lane * 2;
#pragma unroll
    for (int h = 0; h < 8; h++) {
        unsigned lo = f2bf(acc[h].x * inv[h]);
        unsigned hi = f2bf(acc[h].y * inv[h]);
        *(unsigned*)(dst + h * 128) = lo | (hi << 16);   // coalesced per head
    }
}

// ---------------- l12_gemm (MFMA, fused): LDS hbuf -> h2, as2/ad2 ----------------
// Block = 16 nodes (N=10000 -> exactly 625 tiles).
// Phase A: wave w computes col-tiles ct = w*16..w*16+15 of ELU(y@W1+b1) -> LDS
//          (row stride 1032 shorts: <=2-way banks).
// Phase B: wave w computes h2 cols w*16..+15 (K=1024 from LDS) + alpha2 logits.

__global__ __launch_bounds__(256) void l12_gemm(
    const unsigned short* __restrict__ y_b, const unsigned short* __restrict__ W1bT,
    const float* __restrict__ b1, const unsigned short* __restrict__ W2bT,
    const float* __restrict__ a_src2, const float* __restrict__ a_dst2,
    float* __restrict__ h2, float* __restrict__ as2, float* __restrict__ ad2, int N) {
    int nb = blockIdx.x * 16;
    int w = threadIdx.x >> 6;
    int lane = threadIdx.x & 63;
    int n16 = lane & 15, quad = lane >> 4;
    __shared__ unsigned short hb[16 * 1032];   // 33 KB
    __shared__ float sA[4][16], sD[4][16];
    // ---- phase A ----
    int node_a = nb + n16;
    const unsigned short* yrow = y_b + (size_t)(node_a < N ? node_a : 0) * 1024;
#pragma unroll
    for (int cti = 0; cti < 16; cti++) {
        int ct = w * 16 + cti;          // 0..63
        int h = ct >> 3;
        int cc = (ct & 7) * 16;
        const unsigned short* Wh = W1bT + h * 16384 + (size_t)(cc + n16) * 128 + quad * 8;
        const unsigned short* ya = yrow + h * 128 + quad * 8;
        f32x4 acc = (f32x4){0.f, 0.f, 0.f, 0.f};
#pragma unroll
        for (int ks = 0; ks < 4; ks++) {
            bf16x8 a = *(const bf16x8*)(ya + ks * 32);
            bf16x8 b = *(const bf16x8*)(Wh + ks * 32);
            acc = __builtin_amdgcn_mfma_f32_16x16x32_bf16(a, b, acc, 0, 0, 0);
        }
        int c = h * 128 + cc + n16;     // global channel
        float bias = b1[c];
#pragma unroll
        for (int r = 0; r < 4; r++) {
            float v = acc[r] + bias;
            v = v > 0.f ? v : expm1f(v);
            hb[(quad * 4 + r) * 1032 + c] = f2bf(v);
        }
    }
    __syncthreads();
    // ---- phase B ----
    const unsigned short* arow = hb + n16 * 1032 + quad * 8;
    const unsigned short* brow = W2bT + (size_t)(w * 16 + n16) * 1024 + quad * 8;
    f32x4 acc = (f32x4){0.f, 0.f, 0.f, 0.f};
#pragma unroll 8
    for (int ks = 0; ks < 32; ks++) {
        bf16x8 a = *(const bf16x8*)(arow + ks * 32);
        bf16x8 b = *(const bf16x8*)(brow + ks * 32);
        acc = __builtin_amdgcn_mfma_f32_16x16x32_bf16(a, b, acc, 0, 0, 0);
    }
    int c2 = w * 16 + n16;
    float asc = a_src2[c2], adc = a_dst2[c2];
    float pav[4], pdv[4];
#pragma unroll
    for (int r = 0; r < 4; r++) {
        int node = nb + quad * 4 + r;
        if (node < N) h2[(size_t)node * 64 + c2] = acc[r];
        pav[r] = acc[r] * asc;
        pdv[r] = acc[r] * adc;
#pragma unroll
        for (int mm = 1; mm <= 8; mm <<= 1) {   // reduce over the 16 n16 lanes
            pav[r] += __shfl_xor(pav[r], mm);
            pdv[r] += __shfl_xor(pdv[r], mm);
        }
    }
    if (n16 == 0) {
#pragma unroll
        for (int r = 0; r < 4; r++) {
            sA[w][quad * 4 + r] = pav[r];
            sD[w][quad * 4 + r] = pdv[r];
        }
    }
    __syncthreads();
    if (threadIdx.x < 16) {
        int node = nb + threadIdx.x;
        if (node < N) {
            as2[node] = sA[0][threadIdx.x] + sA[1][threadIdx.x] + sA[2][threadIdx.x] + sA[3][threadIdx.x];
            ad2[node] = sD[0][threadIdx.x] + sD[1][threadIdx.x] + sD[2][threadIdx.x] + sD[3][threadIdx.x];
        }
    }
}

// ---------------- l2_gather: wave per node, inline weights, in-register wsum -----

__global__ __launch_bounds__(256) void l2_gather(
    const float* __restrict__ h2, const float* __restrict__ as2,
    const float* __restrict__ ad2, const float* __restrict__ b2,
    const int* __restrict__ offsets, const int* __restrict__ srcs,
    float* __restrict__ out, int N) {
    int n = blockIdx.x * 4 + (threadIdx.x >> 6);
    if (n >= N) return;
    int lane = threadIdx.x & 63;
    int beg = offsets[n];
    int deg = offsets[n + 1] - beg;
    float adn = ad2[n];
    float acc = 0.f, wsum = 0.f;
    int i = 0;
    for (; i + 4 <= deg; i += 4) {
        int s0 = srcs[beg + i],     s1 = srcs[beg + i + 1];
        int s2 = srcs[beg + i + 2], s3 = srcs[beg + i + 3];
        float w0 = __expf(leaky(as2[s0] + adn));   // same addr all lanes -> broadcast
        float w1 = __expf(leaky(as2[s1] + adn));
        float w2 = __expf(leaky(as2[s2] + adn));
        float w3 = __expf(leaky(as2[s3] + adn));
        float v0 = h2[(size_t)s0 * 64 + lane];
        float v1 = h2[(size_t)s1 * 64 + lane];
        float v2 = h2[(size_t)s2 * 64 + lane];
        float v3 = h2[(size_t)s3 * 64 + lane];
        wsum += w0 + w1 + w2 + w3;
        acc = fmaf(w0, v0, acc);
        acc = fmaf(w1, v1, acc);
        acc = fmaf(w2, v2, acc);
        acc = fmaf(w3, v3, acc);
    }
    for (; i < deg; i++) {
        int s = srcs[beg + i];
        float w = __expf(leaky(as2[s] + adn));
        wsum += w;
        acc = fmaf(w, h2[(size_t)s * 64 + lane], acc);
    }
    out[(size_t)n * 64 + lane] = acc / (wsum + 1e-16f) + b2[lane];
}

// ---------------- launch ----------------

static inline size_t align_up(size_t v, size_t a) { return (v + a - 1) / a * a; }

extern "C" void kernel_launch(void* const* d_in, const int* in_sizes, int n_in,
                              void* d_out, int out_size, void* d_ws, size_t ws_size,
                              hipStream_t stream) {
    const float* x      = (const float*)d_in[0];
    const int*   ei     = (const int*)d_in[1];
    const float* W1     = (const float*)d_in[2];
    const float* a_src1 = (const float*)d_in[3];
    const float* a_dst1 = (const float*)d_in[4];
    const float* b1     = (const float*)d_in[5];
    const float* W2     = (const float*)d_in[6];
    const float* a_src2 = (const float*)d_in[7];
    const float* a_dst2 = (const float*)d_in[8];
    const float* b2     = (const float*)d_in[9];
    float* out = (float*)d_out;

    int N = in_sizes[0] / 128;
    int E = in_sizes[1] / 2;
    int M = E + N;

    char* p = (char*)d_ws;
    size_t off = 0;
    auto carve = [&](size_t bytes) {
        void* r = p + off;
        off = align_up(off + bytes, 256);
        return r;
    };
    int*            counts  = (int*)carve((size_t)N * 4);
    int*            offsets = (int*)carve((size_t)(N + 1) * 4);
    int*            cursor  = (int*)carve((size_t)N * 4);
    int*            srcs    = (int*)carve((size_t)M * 4);
    float*          As_t    = (float*)carve(1056 * 4);
    float*          Ad_t    = (float*)carve(1056 * 4);
    float*          as1     = (float*)carve((size_t)N * 8 * 4);
    float*          ad1     = (float*)carve((size_t)N * 8 * 4);
    float*          as2     = (float*)carve((size_t)N * 4);
    float*          ad2     = (float*)carve((size_t)N * 4);
    float*          h2      = (float*)carve((size_t)N * 64 * 4);
    float*          wbuf    = (float*)carve((size_t)M * 8 * 4);
    unsigned short* W1bT    = (unsigned short*)carve((size_t)8 * 128 * 128 * 2);
    unsigned short* W2bT    = (unsigned short*)carve((size_t)64 * 1024 * 2);
    unsigned short* y_b     = (unsigned short*)carve((size_t)N * 1024 * 2);
    (void)ws_size; // ~40 MB

    int nb_count = (M + 255) / 256;
    int nb_alpha = (N + 127) / 128;

    hipMemsetAsync(counts, 0, (size_t)N * 4, stream);
    prep_count<<<196 + nb_count, 256, 0, stream>>>(W1, a_src1, a_dst1, W2, ei,
                                                   As_t, Ad_t, W1bT, W2bT, counts, E, N);
    alpha_scan<<<nb_alpha + 1, 1024, 0, stream>>>(x, As_t, Ad_t, as1, ad1,
                                                  counts, offsets, cursor, N, nb_alpha);
    fill_w1<<<nb_count, 256, 0, stream>>>(ei, cursor, as1, ad1, srcs, wbuf, E, N);
    l1_gather<<<(N + 3) / 4, 256, 0, stream>>>(x, wbuf, offsets, srcs, y_b, N);
    l12_gemm<<<(N + 15) / 16, 256, 0, stream>>>(y_b, W1bT, b1, W2bT, a_src2, a_dst2,
                                                h2, as2, ad2, N);
    l2_gather<<<(N + 3) / 4, 256, 0, stream>>>(h2, as2, ad2, b2, offsets, srcs, out, N);
}